// Round 4
// baseline (1013.588 us; speedup 1.0000x reference)
//
#include <hip/hip_runtime.h>

// ---------------------------------------------------------------------------
// net_lstm: graph-constructor (topk-20 sparse adj) + per-node LSTM (bf16 MFMA)
//           + mixprop x2 (sparse gather + uniform-weight proj) + layernorm.
// Only layer j=2 of the 3 layers affects the output (reference overwrites h).
// ALL tensors are FLOAT32 on device (in_npz_mb=91.5 == fp32 x; out fp32).
// Internal LSTM matmul uses bf16 MFMA (RNE-converted), everything else fp32.
// ---------------------------------------------------------------------------

typedef unsigned short u16;
typedef __attribute__((ext_vector_type(8))) short bf16x8;   // 8 bf16 = 4 VGPR (MFMA A/B frag)
typedef __attribute__((ext_vector_type(4))) float fx4;      // MFMA C/D frag

#define NB 64          // batch
#define NNODE 1000
#define TT 12
#define FF 32
#define HH 64
#define DD 40
#define TOPK_ 20
#define EPR 21         // entries per adjacency row (topk + diagonal)

__device__ __forceinline__ u16 f2b(float f) {               // fp32 -> bf16 RNE
  union { float f; unsigned int i; } v; v.f = f;
  unsigned int i = v.i;
  return (u16)((i + 0x7FFFu + ((i >> 16) & 1u)) >> 16);
}
__device__ __forceinline__ float sigm(float x) { return 1.0f / (1.0f + __expf(-x)); }
__device__ __forceinline__ float tanh_f(float x) {          // NaN-safe: e>=0 always
  float e = __expf(2.0f * x);
  return 1.0f - 2.0f / (e + 1.0f);
}
__device__ __forceinline__ bf16x8 cvt8(const float* p) {    // 8 fp32 -> bf16x8
  bf16x8 r;
  #pragma unroll
  for (int e = 0; e < 8; e++) r[e] = (short)f2b(p[e]);
  return r;
}

// ---------------- K1: m1/m2 = tanh(3*(emb @ w^T + b)) -----------------------
__global__ void k_m1m2(const float* __restrict__ emb1, const float* __restrict__ emb2,
                       const float* __restrict__ w1, const float* __restrict__ b1,
                       const float* __restrict__ w2, const float* __restrict__ b2,
                       float* __restrict__ m1, float* __restrict__ m2) {
  int id = blockIdx.x * 256 + threadIdx.x;
  if (id >= 2 * NNODE * DD) return;
  int sel = id / (NNODE * DD);
  int r = id % (NNODE * DD);
  int i = r / DD, o = r % DD;
  const float* emb = sel ? emb2 : emb1;
  const float* w = sel ? w2 : w1;
  const float* bb = sel ? b2 : b1;
  float s = bb[o];
  for (int k = 0; k < DD; k++) s = fmaf(emb[i * DD + k], w[o * DD + k], s);
  (sel ? m2 : m1)[r] = tanh_f(3.0f * s);
}

// ---------------- K2: adjacency row + top-20 + normalize --------------------
// Row v of a = relu(tanh(3*(m1 v . m2 w - m2 v . m1 w))); diag is exactly 0, so
// adj = a*mask + I has diag exactly 1. Sparse output: EPR (idx,val) per row,
// entry 0 is the diagonal. Tie-break: value desc, index asc (matches lax.top_k;
// zero-valued selections contribute nothing so exact zero-tie order is moot).
__global__ void k_adj(const float* __restrict__ m1, const float* __restrict__ m2,
                      float* __restrict__ aval, int* __restrict__ aidx) {
  int v = blockIdx.x, tid = threadIdx.x;
  int lane = tid & 63, wave = tid >> 6;
  __shared__ float arow[NNODE];
  __shared__ float m1v[DD], m2v[DD];
  __shared__ float wv[4]; __shared__ int wi4[4];
  __shared__ float s_val[TOPK_]; __shared__ int s_idx[TOPK_];
  if (tid < DD) { m1v[tid] = m1[v * DD + tid]; m2v[tid] = m2[v * DD + tid]; }
  __syncthreads();
  for (int w = tid; w < NNODE; w += 256) {
    float d1 = 0.f, d2 = 0.f;
    #pragma unroll 8
    for (int k = 0; k < DD; k++) {
      d1 = fmaf(m1v[k], m2[w * DD + k], d1);
      d2 = fmaf(m2v[k], m1[w * DD + k], d2);
    }
    arow[w] = fmaxf(tanh_f(3.0f * (d1 - d2)), 0.0f);
  }
  __syncthreads();
  for (int sel = 0; sel < TOPK_; sel++) {
    float bv = -1.f; int bi = NNODE;
    for (int w = tid; w < NNODE; w += 256) {
      float xx = arow[w];
      if (xx > bv) { bv = xx; bi = w; }        // ascending scan => lowest idx on tie
    }
    for (int off = 32; off; off >>= 1) {
      float ov = __shfl_down(bv, off); int oi = __shfl_down(bi, off);
      if (ov > bv || (ov == bv && oi < bi)) { bv = ov; bi = oi; }
    }
    if (lane == 0) { wv[wave] = bv; wi4[wave] = bi; }
    __syncthreads();
    if (tid == 0) {
      float best = wv[0]; int besti = wi4[0];
      for (int t = 1; t < 4; t++)
        if (wv[t] > best || (wv[t] == best && wi4[t] < besti)) { best = wv[t]; besti = wi4[t]; }
      s_val[sel] = best; s_idx[sel] = besti;
      arow[besti] = -1.f;
    }
    __syncthreads();
  }
  if (tid == 0) {
    float rs = 1.0f;                       // diagonal contributes 1
    for (int e = 0; e < TOPK_; e++) rs += s_val[e];
    float inv = 1.0f / rs;
    aval[v * EPR] = inv; aidx[v * EPR] = v;
    for (int e = 0; e < TOPK_; e++) { aval[v * EPR + 1 + e] = s_val[e] * inv; aidx[v * EPR + 1 + e] = s_idx[e]; }
  }
}

// ---------------- K3: LSTM over 12 steps, bf16 MFMA -------------------------
// Block = 256 thr = 4 waves; wave owns 16 sequences, computes all 256 gate cols.
// mfma_f32_16x16x32_bf16: A frag row=lane&15, k=(lane>>4)*8+e (consecutive 8);
// B frag col=lane&15 same k; D col=lane&15, row=(lane>>4)*4+reg  [m89/m92].
// Gate col = gate*64 + j  =>  i/f/g/o for hidden j live in the SAME lane
// (tiles nt, nt+4, nt+8, nt+12) => lane-local nonlinear update. h recirculates
// via an LDS shuttle with __syncthreads() between write(t) and read(t+1).
// Whh fragments stay in LDS; tile visit order rotates with t ((nt+t)&15) so
// the fragment loads are loop-variant => LICM cannot hoist 128 VGPRs of
// fragments out of the t-loop.
__global__ __launch_bounds__(256, 2)
void k_lstm(const float* __restrict__ x, const float* __restrict__ Wih,
            const float* __restrict__ Whh, const float* __restrict__ bih,
            const float* __restrict__ bhh, float* __restrict__ hout) {
  __shared__ __align__(16) u16 whf[2 * 16 * 64 * 8];  // Whh frags [ks][nt][lane][8] (32 KB)
  __shared__ __align__(16) u16 hsh[4][16][64];        // per-wave h shuttle (8 KB)
  int tid = threadIdx.x, wave = tid >> 6, lane = tid & 63;
  int arow = lane & 15, kg = lane >> 4;

  // stage Whh fragments: frag(ks,nt,lane,e) = Whh[col=nt*16+(lane&15)][ks*32+(lane>>4)*8+e]
  for (int c = tid; c < 2 * 16 * 64; c += 256) {
    int l = c & 63, t16 = c >> 6, ks = t16 >> 4, nt = t16 & 15;
    int col = nt * 16 + (l & 15);
    *(bf16x8*)&whf[c * 8] = cvt8(Whh + col * 64 + ks * 32 + (l >> 4) * 8);
  }
  __syncthreads();

  bf16x8 wi[16];                                      // Wih fragments in registers
  #pragma unroll
  for (int nt = 0; nt < 16; nt++)
    wi[nt] = cvt8(Wih + (nt * 16 + arow) * 32 + kg * 8);
  float biasv[16];
  #pragma unroll
  for (int nt = 0; nt < 16; nt++) {
    int col = nt * 16 + arow;
    biasv[nt] = bih[col] + bhh[col];
  }

  int seq_base = blockIdx.x * 64 + wave * 16;
  const float* xb = x + (size_t)(seq_base + arow) * (TT * FF) + kg * 8;
  float cst[16];
  #pragma unroll
  for (int q = 0; q < 16; q++) cst[q] = 0.f;
  fx4 acc[16];

  #pragma unroll 1
  for (int t = 0; t < TT; t++) {
    #pragma unroll
    for (int nt = 0; nt < 16; nt++)
      acc[nt] = (fx4){biasv[nt], biasv[nt], biasv[nt], biasv[nt]};
    bf16x8 xa = cvt8(xb + t * FF);
    #pragma unroll
    for (int nt = 0; nt < 16; nt++)
      acc[nt] = __builtin_amdgcn_mfma_f32_16x16x32_bf16(xa, wi[nt], acc[nt], 0, 0, 0);
    if (t > 0) {
      __syncthreads();                   // h shuttle: write(t-1) -> read(t)
      bf16x8 ha0 = *(const bf16x8*)&hsh[wave][arow][kg * 8];
      bf16x8 ha1 = *(const bf16x8*)&hsh[wave][arow][32 + kg * 8];
      #pragma unroll
      for (int nt = 0; nt < 16; nt++) {
        int ntp = (nt + t) & 15;         // loop-variant address: blocks LICM
        bf16x8 wb = *(const bf16x8*)&whf[(ntp * 64 + lane) * 8];
        acc[ntp] = __builtin_amdgcn_mfma_f32_16x16x32_bf16(ha0, wb, acc[ntp], 0, 0, 0);
      }
      #pragma unroll
      for (int nt = 0; nt < 16; nt++) {
        int ntp = (nt + t) & 15;
        bf16x8 wb = *(const bf16x8*)&whf[((16 + ntp) * 64 + lane) * 8];
        acc[ntp] = __builtin_amdgcn_mfma_f32_16x16x32_bf16(ha1, wb, acc[ntp], 0, 0, 0);
      }
    }
    // gates: hidden j = njt*16+arow; rows (=sequences within wave) kg*4+i
    #pragma unroll
    for (int i = 0; i < 4; i++) {
      #pragma unroll
      for (int njt = 0; njt < 4; njt++) {
        float iv = acc[njt][i], fv = acc[njt + 4][i];
        float gv = acc[njt + 8][i], ov = acc[njt + 12][i];
        float cprev = cst[i * 4 + njt];
        float c = sigm(fv) * cprev + sigm(iv) * tanh_f(gv);
        cst[i * 4 + njt] = c;
        hsh[wave][kg * 4 + i][njt * 16 + arow] = f2b(sigm(ov) * tanh_f(c));
      }
    }
  }
  // final h: each thread re-reads exactly the addresses it wrote (per-thread
  // same-address dependency -> ordered without a barrier)
  #pragma unroll
  for (int i = 0; i < 4; i++)
    #pragma unroll
    for (int njt = 0; njt < 4; njt++) {
      union { unsigned int u; float f; } cv;
      cv.u = ((unsigned int)hsh[wave][kg * 4 + i][njt * 16 + arow]) << 16;
      hout[(size_t)(seq_base + kg * 4 + i) * HH + njt * 16 + arow] = cv.f;
    }
}

// ---------------- K_prep: layer-2 weights transposed into ws ----------------
// wt layout (all fp32): [0..767] lin_w^T [k][s]; [768..779] lin_b;
// [784..1935] mp1_w^T [c][o=32]; [1936..1967] mp1_b;
// [1968..5807] mp2_w^T [c][o=40]; [5808..5847] mp2_b.
__global__ void k_prep(const float* __restrict__ lw, const float* __restrict__ lb,
                       const float* __restrict__ w1, const float* __restrict__ b1,
                       const float* __restrict__ w2, const float* __restrict__ b2,
                       float* __restrict__ wt) {
  int tid = threadIdx.x;
  for (int i = tid; i < 768; i += 256) { int k = i / 12, s = i % 12; wt[i] = lw[s * 64 + k]; }
  if (tid < 12) wt[768 + tid] = lb[tid];
  for (int i = tid; i < 1152; i += 256) { int c = i / 32, o = i % 32; wt[784 + i] = w1[o * 36 + c]; }
  if (tid < 32) wt[1936 + tid] = b1[tid];
  for (int i = tid; i < 3840; i += 256) { int c = i / 40, o = i % 40; wt[1968 + i] = w2[o * 96 + c]; }
  if (tid < 40) wt[5808 + tid] = b2[tid];
}

// ---------------- K4: hj[b][s][n] = h[b*1000+n] . lin_w2[s] + lin_b2[s] -----
__global__ void k_hj(const float* __restrict__ h, const float* __restrict__ wt,
                     float* __restrict__ hj) {
  int id = blockIdx.x * 256 + threadIdx.x;     // (b,n), 64000 total
  int b = id / NNODE, n = id % NNODE;
  const float* hr = h + (size_t)id * HH;
  float hv[HH];
  #pragma unroll
  for (int k = 0; k < HH; k += 4) {
    float4 t4 = *(const float4*)(hr + k);
    hv[k] = t4.x; hv[k + 1] = t4.y; hv[k + 2] = t4.z; hv[k + 3] = t4.w;
  }
  float acc[12];
  #pragma unroll
  for (int s = 0; s < 12; s++) acc[s] = wt[768 + s];
  for (int k = 0; k < HH; k++) {
    float hvk = hv[k];
    #pragma unroll
    for (int s = 0; s < 12; s++) acc[s] = fmaf(hvk, wt[k * 12 + s], acc[s]);  // uniform -> SGPR
  }
  #pragma unroll
  for (int s = 0; s < 12; s++) hj[(size_t)(b * 12 + s) * NNODE + n] = acc[s];
}

// ---------------- K5/K7: mixprop propagation (gdep=2) -----------------------
// block = b*C + c. ho[b][d*C+c][:] for d=0,1,2 with h_{k+1}=0.05*x0+0.95*A h_k.
__global__ void k_prop(const float* __restrict__ hin, const float* __restrict__ aval,
                       const int* __restrict__ aidx, float* __restrict__ ho, int C) {
  int blk = blockIdx.x;
  int b = blk / C, c = blk % C;
  __shared__ float r0[NNODE], r1[NNODE];
  int tid = threadIdx.x;
  const float* src = hin + (size_t)(b * C + c) * NNODE;
  float* dst = ho + (size_t)(b * 3 * C) * NNODE;
  for (int n = tid; n < NNODE; n += 256) {
    float vv = src[n]; r0[n] = vv; dst[(size_t)c * NNODE + n] = vv;
  }
  __syncthreads();
  for (int n = tid; n < NNODE; n += 256) {
    const float* av = aval + n * EPR; const int* ai = aidx + n * EPR;
    float s = 0.f;
    #pragma unroll
    for (int e = 0; e < EPR; e++) s = fmaf(av[e], r0[ai[e]], s);
    float h1 = 0.05f * r0[n] + 0.95f * s;
    r1[n] = h1; dst[(size_t)(C + c) * NNODE + n] = h1;
  }
  __syncthreads();
  for (int n = tid; n < NNODE; n += 256) {
    const float* av = aval + n * EPR; const int* ai = aidx + n * EPR;
    float s = 0.f;
    #pragma unroll
    for (int e = 0; e < EPR; e++) s = fmaf(av[e], r1[ai[e]], s);
    dst[(size_t)(2 * C + c) * NNODE + n] = 0.05f * r0[n] + 0.95f * s;
  }
}

// ---------------- K6/K8: channel projection (uniform weights -> SGPR) -------
template <int CIN, int COUT>
__global__ void k_proj(const float* __restrict__ hin, const float* __restrict__ wt,
                       const float* __restrict__ bb, float* __restrict__ out, int relu) {
  int id = blockIdx.x * 256 + threadIdx.x;   // (b,n)
  int b = id / NNODE, n = id % NNODE;
  float acc[COUT];
  #pragma unroll
  for (int o = 0; o < COUT; o++) acc[o] = bb[o];
  for (int c = 0; c < CIN; c++) {
    float hv = hin[(size_t)(b * CIN + c) * NNODE + n];
    #pragma unroll
    for (int o = 0; o < COUT; o++) acc[o] = fmaf(hv, wt[c * COUT + o], acc[o]);
  }
  #pragma unroll
  for (int o = 0; o < COUT; o++) {
    float vv = acc[o];
    if (relu) vv = fmaxf(vv, 0.f);
    out[(size_t)(b * COUT + o) * NNODE + n] = vv;
  }
}

// ---------------- K9: layernorm stats over (40,1000) per batch --------------
__global__ void k_lnstat(const float* __restrict__ hj2, float* __restrict__ stat) {
  int b = blockIdx.x, tid = threadIdx.x, lane = tid & 63, wave = tid >> 6;
  const float* p = hj2 + (size_t)b * DD * NNODE;
  float s = 0.f, q = 0.f;
  for (int i = tid; i < DD * NNODE; i += 256) { float vv = p[i]; s += vv; q = fmaf(vv, vv, q); }
  for (int off = 32; off; off >>= 1) { s += __shfl_down(s, off); q += __shfl_down(q, off); }
  __shared__ float ss[4], sq[4];
  if (lane == 0) { ss[wave] = s; sq[wave] = q; }
  __syncthreads();
  if (tid == 0) {
    float S = ss[0] + ss[1] + ss[2] + ss[3];
    float Q = sq[0] + sq[1] + sq[2] + sq[3];
    float mu = S / (float)(DD * NNODE);
    float var = Q / (float)(DD * NNODE) - mu * mu;
    stat[2 * b] = mu; stat[2 * b + 1] = rsqrtf(var + 1e-5f);
  }
}

// ---------------- K10: apply LN + transpose + fp32 out ----------------------
__global__ void k_lnapply(const float* __restrict__ hj2, const float* __restrict__ stat,
                          const float* __restrict__ gamma, const float* __restrict__ beta,
                          float* __restrict__ out) {
  int id = blockIdx.x * 256 + threadIdx.x;   // (b,n)
  int b = id / NNODE, n = id % NNODE;
  float mu = stat[2 * b], rstd = stat[2 * b + 1];
  size_t obase = (size_t)b * (NNODE * DD) + (size_t)n * DD;
  #pragma unroll
  for (int d = 0; d < DD; d++) {
    float h0 = hj2[(size_t)(b * DD + d) * NNODE + n];
    out[obase + d] = (h0 - mu) * rstd * gamma[d * NNODE + n] + beta[d * NNODE + n];
  }
}

// ---------------- workspace layout (fp32 words) -----------------------------
// 0        m1(40000) | 40000 m2(40000) | 80000 aval(21000) | 101000 aidx(21000 int)
// 122000   h_lstm(4.096M)  [reused by ho2 after K4]
// 4218000  hj(768000) | 4986000 ho1(2.304M) | 7290000 o1(2.048M)
// 122000   ho2(6.144M)  [overlaps dead h_lstm/hj/ho1; ends 6266000 < 7290000]
// 9338000  hj2(2.56M) | 11898000 stat(128) | 11898128 wt(5848)   total ~47.6 MB
#define OFF_M1   0
#define OFF_M2   40000
#define OFF_AVAL 80000
#define OFF_AIDX 101000
#define OFF_H    122000
#define OFF_HJ   4218000
#define OFF_HO1  4986000
#define OFF_O1   7290000
#define OFF_HO2  122000
#define OFF_HJ2  9338000
#define OFF_STAT 11898000
#define OFF_WT   11898128

extern "C" void kernel_launch(void* const* d_in, const int* in_sizes, int n_in,
                              void* d_out, int out_size, void* d_ws, size_t ws_size,
                              hipStream_t stream) {
  (void)in_sizes; (void)n_in; (void)out_size; (void)ws_size;
  const float* x     = (const float*)d_in[0];
  const float* emb1  = (const float*)d_in[1];
  const float* emb2  = (const float*)d_in[2];
  const float* l1w   = (const float*)d_in[3];
  const float* l1b   = (const float*)d_in[4];
  const float* l2w   = (const float*)d_in[5];
  const float* l2b   = (const float*)d_in[6];
  const float* Wih   = (const float*)d_in[7];
  const float* Whh   = (const float*)d_in[8];
  const float* bih   = (const float*)d_in[9];
  const float* bhh   = (const float*)d_in[10];
  const float* lin_w = (const float*)d_in[11];
  const float* lin_b = (const float*)d_in[12];
  const float* mp1w  = (const float*)d_in[13];
  const float* mp1b  = (const float*)d_in[14];
  const float* mp2w  = (const float*)d_in[15];
  const float* mp2b  = (const float*)d_in[16];
  const float* gamma = (const float*)d_in[17];
  const float* beta  = (const float*)d_in[18];

  float* ws   = (float*)d_ws;
  float* m1   = ws + OFF_M1;
  float* m2   = ws + OFF_M2;
  float* aval = ws + OFF_AVAL;
  int*   aidx = (int*)(ws + OFF_AIDX);
  float* hl   = ws + OFF_H;
  float* hj   = ws + OFF_HJ;
  float* ho1  = ws + OFF_HO1;
  float* o1   = ws + OFF_O1;
  float* ho2  = ws + OFF_HO2;
  float* hj2  = ws + OFF_HJ2;
  float* stat = ws + OFF_STAT;
  float* wt   = ws + OFF_WT;

  k_m1m2<<<dim3(313), dim3(256), 0, stream>>>(emb1, emb2, l1w, l1b, l2w, l2b, m1, m2);
  k_prep<<<dim3(1), dim3(256), 0, stream>>>(lin_w + 1536, lin_b + 24, mp1w + 2304, mp1b + 64,
                                            mp2w + 7680, mp2b + 80, wt);
  k_adj<<<dim3(NNODE), dim3(256), 0, stream>>>(m1, m2, aval, aidx);
  k_lstm<<<dim3(1000), dim3(256), 0, stream>>>(x, Wih, Whh, bih, bhh, hl);
  k_hj<<<dim3(250), dim3(256), 0, stream>>>(hl, wt, hj);
  k_prop<<<dim3(64 * 12), dim3(256), 0, stream>>>(hj, aval, aidx, ho1, 12);
  k_proj<36, 32><<<dim3(250), dim3(256), 0, stream>>>(ho1, wt + 784, wt + 1936, o1, 1);
  k_prop<<<dim3(64 * 32), dim3(256), 0, stream>>>(o1, aval, aidx, ho2, 32);
  k_proj<96, 40><<<dim3(250), dim3(256), 0, stream>>>(ho2, wt + 1968, wt + 5808, hj2, 0);
  k_lnstat<<<dim3(NB), dim3(256), 0, stream>>>(hj2, stat);
  k_lnapply<<<dim3(250), dim3(256), 0, stream>>>(hj2, stat, gamma + 80000, beta + 80000,
                                                 (float*)d_out);
}

// Round 5
// 402.518 us; speedup vs baseline: 2.5181x; 2.5181x over previous
//
#include <hip/hip_runtime.h>

// ---------------------------------------------------------------------------
// net_lstm: graph-constructor (topk-20 sparse adj) + per-node LSTM (bf16 MFMA)
//           + mixprop x2 (sparse gather + uniform-weight proj) + layernorm.
// Only layer j=2 of the 3 layers affects the output (reference overwrites h).
// ALL tensors are FLOAT32 on device. LSTM matmul in bf16 MFMA, rest fp32.
// ---------------------------------------------------------------------------

typedef unsigned short u16;
typedef __attribute__((ext_vector_type(8))) short bf16x8;   // 8 bf16 = 4 VGPR (MFMA A/B frag)
typedef __attribute__((ext_vector_type(4))) float fx4;      // MFMA C/D frag

#define NB 64          // batch
#define NNODE 1000
#define TT 12
#define FF 32
#define HH 64
#define DD 40
#define TOPK_ 20
#define EPR 21         // entries per adjacency row (topk + diagonal)

__device__ __forceinline__ u16 f2b(float f) {               // fp32 -> bf16 RNE
  union { float f; unsigned int i; } v; v.f = f;
  unsigned int i = v.i;
  return (u16)((i + 0x7FFFu + ((i >> 16) & 1u)) >> 16);
}
__device__ __forceinline__ float sigm(float x) { return 1.0f / (1.0f + __expf(-x)); }
__device__ __forceinline__ float tanh_f(float x) {          // NaN-safe: e>=0 always
  float e = __expf(2.0f * x);
  return 1.0f - 2.0f / (e + 1.0f);
}
__device__ __forceinline__ bf16x8 cvt8(const float* p) {    // 8 fp32 -> bf16x8
  bf16x8 r;
  #pragma unroll
  for (int e = 0; e < 8; e++) r[e] = (short)f2b(p[e]);
  return r;
}

// ---------------- K1: m1/m2 = tanh(3*(emb @ w^T + b)) -----------------------
__global__ void k_m1m2(const float* __restrict__ emb1, const float* __restrict__ emb2,
                       const float* __restrict__ w1, const float* __restrict__ b1,
                       const float* __restrict__ w2, const float* __restrict__ b2,
                       float* __restrict__ m1, float* __restrict__ m2) {
  int id = blockIdx.x * 256 + threadIdx.x;
  if (id >= 2 * NNODE * DD) return;
  int sel = id / (NNODE * DD);
  int r = id % (NNODE * DD);
  int i = r / DD, o = r % DD;
  const float* emb = sel ? emb2 : emb1;
  const float* w = sel ? w2 : w1;
  const float* bb = sel ? b2 : b1;
  float s = bb[o];
  for (int k = 0; k < DD; k++) s = fmaf(emb[i * DD + k], w[o * DD + k], s);
  (sel ? m2 : m1)[r] = tanh_f(3.0f * s);
}

// ---------------- K2: adjacency row + top-20 + normalize --------------------
// Row v of a = relu(tanh(3*(m1 v . m2 w - m2 v . m1 w))); diag is exactly 0, so
// adj = a*mask + I has diag exactly 1. Sparse output: EPR (idx,val) per row,
// entry 0 is the diagonal. Tie-break: value desc, index asc (matches lax.top_k;
// zero-valued selections contribute nothing so exact zero-tie order is moot).
__global__ void k_adj(const float* __restrict__ m1, const float* __restrict__ m2,
                      float* __restrict__ aval, int* __restrict__ aidx) {
  int v = blockIdx.x, tid = threadIdx.x;
  int lane = tid & 63, wave = tid >> 6;
  __shared__ float arow[NNODE];
  __shared__ float m1v[DD], m2v[DD];
  __shared__ float wv[4]; __shared__ int wi4[4];
  __shared__ float s_val[TOPK_]; __shared__ int s_idx[TOPK_];
  if (tid < DD) { m1v[tid] = m1[v * DD + tid]; m2v[tid] = m2[v * DD + tid]; }
  __syncthreads();
  for (int w = tid; w < NNODE; w += 256) {
    float d1 = 0.f, d2 = 0.f;
    #pragma unroll 8
    for (int k = 0; k < DD; k++) {
      d1 = fmaf(m1v[k], m2[w * DD + k], d1);
      d2 = fmaf(m2v[k], m1[w * DD + k], d2);
    }
    arow[w] = fmaxf(tanh_f(3.0f * (d1 - d2)), 0.0f);
  }
  __syncthreads();
  for (int sel = 0; sel < TOPK_; sel++) {
    float bv = -1.f; int bi = NNODE;
    for (int w = tid; w < NNODE; w += 256) {
      float xx = arow[w];
      if (xx > bv) { bv = xx; bi = w; }        // ascending scan => lowest idx on tie
    }
    for (int off = 32; off; off >>= 1) {
      float ov = __shfl_down(bv, off); int oi = __shfl_down(bi, off);
      if (ov > bv || (ov == bv && oi < bi)) { bv = ov; bi = oi; }
    }
    if (lane == 0) { wv[wave] = bv; wi4[wave] = bi; }
    __syncthreads();
    if (tid == 0) {
      float best = wv[0]; int besti = wi4[0];
      for (int t = 1; t < 4; t++)
        if (wv[t] > best || (wv[t] == best && wi4[t] < besti)) { best = wv[t]; besti = wi4[t]; }
      s_val[sel] = best; s_idx[sel] = besti;
      arow[besti] = -1.f;
    }
    __syncthreads();
  }
  if (tid == 0) {
    float rs = 1.0f;                       // diagonal contributes 1
    for (int e = 0; e < TOPK_; e++) rs += s_val[e];
    float inv = 1.0f / rs;
    aval[v * EPR] = inv; aidx[v * EPR] = v;
    for (int e = 0; e < TOPK_; e++) { aval[v * EPR + 1 + e] = s_val[e] * inv; aidx[v * EPR + 1 + e] = s_idx[e]; }
  }
}

// ---------------- K3: LSTM over 12 steps, bf16 MFMA -------------------------
// Block = 256 thr = 4 waves; wave owns 16 sequences, computes all 256 gate cols.
// mfma_f32_16x16x32_bf16: A frag row=lane&15, k=(lane>>4)*8+e (consecutive 8);
// B frag col=lane&15 same k; D col=lane&15, row=(lane>>4)*4+reg  [m89/m92].
// Gate col = gate*64 + j  =>  i/f/g/o for hidden j live in the SAME lane
// (tiles nt, nt+4, nt+8, nt+12) => lane-local nonlinear update. h recirculates
// via an LDS shuttle with __syncthreads() between write(t) and read(t+1).
// Whh fragments stay in LDS, re-read each t. The opaque-zero byte offset (zo,
// re-asm'd every iteration) makes the load addresses loop-VARIANT so LICM
// cannot hoist 128 VGPRs of fragments out of the t-loop. acc[] indexing is
// fully STATIC (rule #20: runtime-indexed vector arrays go to scratch — the
// round-3 (nt+t)&15 rotation caused 1.9 GB of scratch writes, 890us).
__global__ __launch_bounds__(256, 2)
void k_lstm(const float* __restrict__ x, const float* __restrict__ Wih,
            const float* __restrict__ Whh, const float* __restrict__ bih,
            const float* __restrict__ bhh, float* __restrict__ hout) {
  __shared__ __align__(16) u16 whf[2 * 16 * 64 * 8];  // Whh frags [ks][nt][lane][8] (32 KB)
  __shared__ __align__(16) u16 hsh[4][16][64];        // per-wave h shuttle (8 KB)
  int tid = threadIdx.x, wave = tid >> 6, lane = tid & 63;
  int arow = lane & 15, kg = lane >> 4;

  // stage Whh fragments: frag(ks,nt,lane,e) = Whh[col=nt*16+(lane&15)][ks*32+(lane>>4)*8+e]
  for (int c = tid; c < 2 * 16 * 64; c += 256) {
    int l = c & 63, t16 = c >> 6, ks = t16 >> 4, nt = t16 & 15;
    int col = nt * 16 + (l & 15);
    *(bf16x8*)&whf[c * 8] = cvt8(Whh + col * 64 + ks * 32 + (l >> 4) * 8);
  }
  __syncthreads();

  bf16x8 wi[16];                                      // Wih fragments in registers
  #pragma unroll
  for (int nt = 0; nt < 16; nt++)
    wi[nt] = cvt8(Wih + (nt * 16 + arow) * 32 + kg * 8);
  float biasv[16];
  #pragma unroll
  for (int nt = 0; nt < 16; nt++) {
    int col = nt * 16 + arow;
    biasv[nt] = bih[col] + bhh[col];
  }

  int seq_base = blockIdx.x * 64 + wave * 16;
  const float* xb = x + (size_t)(seq_base + arow) * (TT * FF) + kg * 8;
  float cst[16];
  #pragma unroll
  for (int q = 0; q < 16; q++) cst[q] = 0.f;
  fx4 acc[16];

  #pragma unroll 1
  for (int t = 0; t < TT; t++) {
    unsigned int zo = 0;                 // opaque zero, renewed each iteration:
    asm volatile("" : "+v"(zo));         // whf load addrs loop-variant => no LICM
    #pragma unroll
    for (int nt = 0; nt < 16; nt++)
      acc[nt] = (fx4){biasv[nt], biasv[nt], biasv[nt], biasv[nt]};
    bf16x8 xa = cvt8(xb + t * FF);
    #pragma unroll
    for (int nt = 0; nt < 16; nt++)
      acc[nt] = __builtin_amdgcn_mfma_f32_16x16x32_bf16(xa, wi[nt], acc[nt], 0, 0, 0);
    if (t > 0) {
      __syncthreads();                   // h shuttle: write(t-1) -> read(t)
      bf16x8 ha0 = *(const bf16x8*)&hsh[wave][arow][kg * 8];
      bf16x8 ha1 = *(const bf16x8*)&hsh[wave][arow][32 + kg * 8];
      #pragma unroll
      for (int nt = 0; nt < 16; nt++) {
        bf16x8 wb = *(const bf16x8*)&whf[(nt * 64 + lane) * 8 + zo];
        acc[nt] = __builtin_amdgcn_mfma_f32_16x16x32_bf16(ha0, wb, acc[nt], 0, 0, 0);
      }
      #pragma unroll
      for (int nt = 0; nt < 16; nt++) {
        bf16x8 wb = *(const bf16x8*)&whf[((16 + nt) * 64 + lane) * 8 + zo];
        acc[nt] = __builtin_amdgcn_mfma_f32_16x16x32_bf16(ha1, wb, acc[nt], 0, 0, 0);
      }
    }
    // gates: hidden j = njt*16+arow; rows (=sequences within wave) kg*4+i
    #pragma unroll
    for (int i = 0; i < 4; i++) {
      #pragma unroll
      for (int njt = 0; njt < 4; njt++) {
        float iv = acc[njt][i], fv = acc[njt + 4][i];
        float gv = acc[njt + 8][i], ov = acc[njt + 12][i];
        float cprev = cst[i * 4 + njt];
        float c = sigm(fv) * cprev + sigm(iv) * tanh_f(gv);
        cst[i * 4 + njt] = c;
        hsh[wave][kg * 4 + i][njt * 16 + arow] = f2b(sigm(ov) * tanh_f(c));
      }
    }
  }
  // final h: each thread re-reads exactly the addresses it wrote (per-thread
  // same-address dependency -> ordered without a barrier)
  #pragma unroll
  for (int i = 0; i < 4; i++)
    #pragma unroll
    for (int njt = 0; njt < 4; njt++) {
      union { unsigned int u; float f; } cv;
      cv.u = ((unsigned int)hsh[wave][kg * 4 + i][njt * 16 + arow]) << 16;
      hout[(size_t)(seq_base + kg * 4 + i) * HH + njt * 16 + arow] = cv.f;
    }
}

// ---------------- K_prep: layer-2 weights transposed into ws ----------------
// wt layout (all fp32): [0..767] lin_w^T [k][s]; [768..779] lin_b;
// [784..1935] mp1_w^T [c][o=32]; [1936..1967] mp1_b;
// [1968..5807] mp2_w^T [c][o=40]; [5808..5847] mp2_b.
__global__ void k_prep(const float* __restrict__ lw, const float* __restrict__ lb,
                       const float* __restrict__ w1, const float* __restrict__ b1,
                       const float* __restrict__ w2, const float* __restrict__ b2,
                       float* __restrict__ wt) {
  int tid = threadIdx.x;
  for (int i = tid; i < 768; i += 256) { int k = i / 12, s = i % 12; wt[i] = lw[s * 64 + k]; }
  if (tid < 12) wt[768 + tid] = lb[tid];
  for (int i = tid; i < 1152; i += 256) { int c = i / 32, o = i % 32; wt[784 + i] = w1[o * 36 + c]; }
  if (tid < 32) wt[1936 + tid] = b1[tid];
  for (int i = tid; i < 3840; i += 256) { int c = i / 40, o = i % 40; wt[1968 + i] = w2[o * 96 + c]; }
  if (tid < 40) wt[5808 + tid] = b2[tid];
}

// ---------------- K4: hj[b][s][n] = h[b*1000+n] . lin_w2[s] + lin_b2[s] -----
__global__ void k_hj(const float* __restrict__ h, const float* __restrict__ wt,
                     float* __restrict__ hj) {
  int id = blockIdx.x * 256 + threadIdx.x;     // (b,n), 64000 total
  int b = id / NNODE, n = id % NNODE;
  const float* hr = h + (size_t)id * HH;
  float hv[HH];
  #pragma unroll
  for (int k = 0; k < HH; k += 4) {
    float4 t4 = *(const float4*)(hr + k);
    hv[k] = t4.x; hv[k + 1] = t4.y; hv[k + 2] = t4.z; hv[k + 3] = t4.w;
  }
  float acc[12];
  #pragma unroll
  for (int s = 0; s < 12; s++) acc[s] = wt[768 + s];
  for (int k = 0; k < HH; k++) {
    float hvk = hv[k];
    #pragma unroll
    for (int s = 0; s < 12; s++) acc[s] = fmaf(hvk, wt[k * 12 + s], acc[s]);  // uniform -> SGPR
  }
  #pragma unroll
  for (int s = 0; s < 12; s++) hj[(size_t)(b * 12 + s) * NNODE + n] = acc[s];
}

// ---------------- K5/K7: mixprop propagation (gdep=2) -----------------------
// block = b*C + c. ho[b][d*C+c][:] for d=0,1,2 with h_{k+1}=0.05*x0+0.95*A h_k.
__global__ void k_prop(const float* __restrict__ hin, const float* __restrict__ aval,
                       const int* __restrict__ aidx, float* __restrict__ ho, int C) {
  int blk = blockIdx.x;
  int b = blk / C, c = blk % C;
  __shared__ float r0[NNODE], r1[NNODE];
  int tid = threadIdx.x;
  const float* src = hin + (size_t)(b * C + c) * NNODE;
  float* dst = ho + (size_t)(b * 3 * C) * NNODE;
  for (int n = tid; n < NNODE; n += 256) {
    float vv = src[n]; r0[n] = vv; dst[(size_t)c * NNODE + n] = vv;
  }
  __syncthreads();
  for (int n = tid; n < NNODE; n += 256) {
    const float* av = aval + n * EPR; const int* ai = aidx + n * EPR;
    float s = 0.f;
    #pragma unroll
    for (int e = 0; e < EPR; e++) s = fmaf(av[e], r0[ai[e]], s);
    float h1 = 0.05f * r0[n] + 0.95f * s;
    r1[n] = h1; dst[(size_t)(C + c) * NNODE + n] = h1;
  }
  __syncthreads();
  for (int n = tid; n < NNODE; n += 256) {
    const float* av = aval + n * EPR; const int* ai = aidx + n * EPR;
    float s = 0.f;
    #pragma unroll
    for (int e = 0; e < EPR; e++) s = fmaf(av[e], r1[ai[e]], s);
    dst[(size_t)(2 * C + c) * NNODE + n] = 0.05f * r0[n] + 0.95f * s;
  }
}

// ---------------- K6/K8: channel projection (uniform weights -> SGPR) -------
template <int CIN, int COUT>
__global__ void k_proj(const float* __restrict__ hin, const float* __restrict__ wt,
                       const float* __restrict__ bb, float* __restrict__ out, int relu) {
  int id = blockIdx.x * 256 + threadIdx.x;   // (b,n)
  int b = id / NNODE, n = id % NNODE;
  float acc[COUT];
  #pragma unroll
  for (int o = 0; o < COUT; o++) acc[o] = bb[o];
  for (int c = 0; c < CIN; c++) {
    float hv = hin[(size_t)(b * CIN + c) * NNODE + n];
    #pragma unroll
    for (int o = 0; o < COUT; o++) acc[o] = fmaf(hv, wt[c * COUT + o], acc[o]);
  }
  #pragma unroll
  for (int o = 0; o < COUT; o++) {
    float vv = acc[o];
    if (relu) vv = fmaxf(vv, 0.f);
    out[(size_t)(b * COUT + o) * NNODE + n] = vv;
  }
}

// ---------------- K9: layernorm stats over (40,1000) per batch --------------
__global__ void k_lnstat(const float* __restrict__ hj2, float* __restrict__ stat) {
  int b = blockIdx.x, tid = threadIdx.x, lane = tid & 63, wave = tid >> 6;
  const float* p = hj2 + (size_t)b * DD * NNODE;
  float s = 0.f, q = 0.f;
  for (int i = tid; i < DD * NNODE; i += 256) { float vv = p[i]; s += vv; q = fmaf(vv, vv, q); }
  for (int off = 32; off; off >>= 1) { s += __shfl_down(s, off); q += __shfl_down(q, off); }
  __shared__ float ss[4], sq[4];
  if (lane == 0) { ss[wave] = s; sq[wave] = q; }
  __syncthreads();
  if (tid == 0) {
    float S = ss[0] + ss[1] + ss[2] + ss[3];
    float Q = sq[0] + sq[1] + sq[2] + sq[3];
    float mu = S / (float)(DD * NNODE);
    float var = Q / (float)(DD * NNODE) - mu * mu;
    stat[2 * b] = mu; stat[2 * b + 1] = rsqrtf(var + 1e-5f);
  }
}

// ---------------- K10: apply LN + transpose + fp32 out ----------------------
__global__ void k_lnapply(const float* __restrict__ hj2, const float* __restrict__ stat,
                          const float* __restrict__ gamma, const float* __restrict__ beta,
                          float* __restrict__ out) {
  int id = blockIdx.x * 256 + threadIdx.x;   // (b,n)
  int b = id / NNODE, n = id % NNODE;
  float mu = stat[2 * b], rstd = stat[2 * b + 1];
  size_t obase = (size_t)b * (NNODE * DD) + (size_t)n * DD;
  #pragma unroll
  for (int d = 0; d < DD; d++) {
    float h0 = hj2[(size_t)(b * DD + d) * NNODE + n];
    out[obase + d] = (h0 - mu) * rstd * gamma[d * NNODE + n] + beta[d * NNODE + n];
  }
}

// ---------------- workspace layout (fp32 words) -----------------------------
// 0        m1(40000) | 40000 m2(40000) | 80000 aval(21000) | 101000 aidx(21000 int)
// 122000   h_lstm(4.096M)  [reused by ho2 after K4]
// 4218000  hj(768000) | 4986000 ho1(2.304M) | 7290000 o1(2.048M)
// 122000   ho2(6.144M)  [overlaps dead h_lstm/hj/ho1; ends 6266000 < 7290000]
// 9338000  hj2(2.56M) | 11898000 stat(128) | 11898128 wt(5848)   total ~47.6 MB
#define OFF_M1   0
#define OFF_M2   40000
#define OFF_AVAL 80000
#define OFF_AIDX 101000
#define OFF_H    122000
#define OFF_HJ   4218000
#define OFF_HO1  4986000
#define OFF_O1   7290000
#define OFF_HO2  122000
#define OFF_HJ2  9338000
#define OFF_STAT 11898000
#define OFF_WT   11898128

extern "C" void kernel_launch(void* const* d_in, const int* in_sizes, int n_in,
                              void* d_out, int out_size, void* d_ws, size_t ws_size,
                              hipStream_t stream) {
  (void)in_sizes; (void)n_in; (void)out_size; (void)ws_size;
  const float* x     = (const float*)d_in[0];
  const float* emb1  = (const float*)d_in[1];
  const float* emb2  = (const float*)d_in[2];
  const float* l1w   = (const float*)d_in[3];
  const float* l1b   = (const float*)d_in[4];
  const float* l2w   = (const float*)d_in[5];
  const float* l2b   = (const float*)d_in[6];
  const float* Wih   = (const float*)d_in[7];
  const float* Whh   = (const float*)d_in[8];
  const float* bih   = (const float*)d_in[9];
  const float* bhh   = (const float*)d_in[10];
  const float* lin_w = (const float*)d_in[11];
  const float* lin_b = (const float*)d_in[12];
  const float* mp1w  = (const float*)d_in[13];
  const float* mp1b  = (const float*)d_in[14];
  const float* mp2w  = (const float*)d_in[15];
  const float* mp2b  = (const float*)d_in[16];
  const float* gamma = (const float*)d_in[17];
  const float* beta  = (const float*)d_in[18];

  float* ws   = (float*)d_ws;
  float* m1   = ws + OFF_M1;
  float* m2   = ws + OFF_M2;
  float* aval = ws + OFF_AVAL;
  int*   aidx = (int*)(ws + OFF_AIDX);
  float* hl   = ws + OFF_H;
  float* hj   = ws + OFF_HJ;
  float* ho1  = ws + OFF_HO1;
  float* o1   = ws + OFF_O1;
  float* ho2  = ws + OFF_HO2;
  float* hj2  = ws + OFF_HJ2;
  float* stat = ws + OFF_STAT;
  float* wt   = ws + OFF_WT;

  k_m1m2<<<dim3(313), dim3(256), 0, stream>>>(emb1, emb2, l1w, l1b, l2w, l2b, m1, m2);
  k_prep<<<dim3(1), dim3(256), 0, stream>>>(lin_w + 1536, lin_b + 24, mp1w + 2304, mp1b + 64,
                                            mp2w + 7680, mp2b + 80, wt);
  k_adj<<<dim3(NNODE), dim3(256), 0, stream>>>(m1, m2, aval, aidx);
  k_lstm<<<dim3(1000), dim3(256), 0, stream>>>(x, Wih, Whh, bih, bhh, hl);
  k_hj<<<dim3(250), dim3(256), 0, stream>>>(hl, wt, hj);
  k_prop<<<dim3(64 * 12), dim3(256), 0, stream>>>(hj, aval, aidx, ho1, 12);
  k_proj<36, 32><<<dim3(250), dim3(256), 0, stream>>>(ho1, wt + 784, wt + 1936, o1, 1);
  k_prop<<<dim3(64 * 32), dim3(256), 0, stream>>>(o1, aval, aidx, ho2, 32);
  k_proj<96, 40><<<dim3(250), dim3(256), 0, stream>>>(ho2, wt + 1968, wt + 5808, hj2, 0);
  k_lnstat<<<dim3(NB), dim3(256), 0, stream>>>(hj2, stat);
  k_lnapply<<<dim3(250), dim3(256), 0, stream>>>(hj2, stat, gamma + 80000, beta + 80000,
                                                 (float*)d_out);
}

// Round 6
// 335.732 us; speedup vs baseline: 3.0190x; 1.1989x over previous
//
#include <hip/hip_runtime.h>

// ---------------------------------------------------------------------------
// net_lstm: graph-constructor (topk-20 sparse adj) + per-node LSTM (bf16 MFMA)
//           + mixprop x2 (sparse gather + uniform-weight proj) + layernorm.
// Only layer j=2 of the 3 layers affects the output (reference overwrites h).
// ALL tensors are FLOAT32 on device. LSTM matmul in bf16 MFMA, rest fp32.
// All reciprocals via v_rcp_f32 (~1ulp; tolerance is 2% of absmax).
// ---------------------------------------------------------------------------

typedef unsigned short u16;
typedef __attribute__((ext_vector_type(8))) short bf16x8;   // 8 bf16 = 4 VGPR (MFMA A/B frag)
typedef __attribute__((ext_vector_type(4))) float fx4;      // MFMA C/D frag

#define NB 64          // batch
#define NNODE 1000
#define TT 12
#define FF 32
#define HH 64
#define DD 40
#define TOPK_ 20
#define EPR 21         // entries per adjacency row (topk + diagonal)

__device__ __forceinline__ float rcp_f(float x) { return __builtin_amdgcn_rcpf(x); }
__device__ __forceinline__ float sigm(float x) { return rcp_f(1.0f + __expf(-x)); }
__device__ __forceinline__ float tanh_f(float x) {          // NaN-safe: e>=0 always
  return fmaf(-2.0f, rcp_f(__expf(2.0f * x) + 1.0f), 1.0f);
}
__device__ __forceinline__ unsigned int cvt_pk(float lo, float hi) {
  unsigned int r;                                           // r = [bf16(hi)|bf16(lo)]
  asm("v_cvt_pk_bf16_f32 %0, %1, %2" : "=v"(r) : "v"(lo), "v"(hi));
  return r;
}
__device__ __forceinline__ bf16x8 cvt8(const float* p) {    // 8 fp32 -> bf16x8 (4 cvt_pk)
  union { unsigned int u[4]; bf16x8 v; } r;
  #pragma unroll
  for (int e = 0; e < 4; e++) r.u[e] = cvt_pk(p[2 * e], p[2 * e + 1]);
  return r.v;
}

// ---------------- K1: m1/m2 = tanh(3*(emb @ w^T + b)) -----------------------
__global__ void k_m1m2(const float* __restrict__ emb1, const float* __restrict__ emb2,
                       const float* __restrict__ w1, const float* __restrict__ b1,
                       const float* __restrict__ w2, const float* __restrict__ b2,
                       float* __restrict__ m1, float* __restrict__ m2) {
  int id = blockIdx.x * 256 + threadIdx.x;
  if (id >= 2 * NNODE * DD) return;
  int sel = id / (NNODE * DD);
  int r = id % (NNODE * DD);
  int i = r / DD, o = r % DD;
  const float* emb = sel ? emb2 : emb1;
  const float* w = sel ? w2 : w1;
  const float* bb = sel ? b2 : b1;
  float s = bb[o];
  for (int k = 0; k < DD; k++) s = fmaf(emb[i * DD + k], w[o * DD + k], s);
  (sel ? m2 : m1)[r] = tanh_f(3.0f * s);
}

// ---------------- K2: adjacency row + top-20 + normalize --------------------
// Row v of a = relu(tanh(3*(m1 v . m2 w - m2 v . m1 w))); diag is exactly 0, so
// adj = a*mask + I has diag exactly 1. Sparse output: packed int2 {idx, val}.
__global__ void k_adj(const float* __restrict__ m1, const float* __restrict__ m2,
                      int2* __restrict__ pae) {
  int v = blockIdx.x, tid = threadIdx.x;
  int lane = tid & 63, wave = tid >> 6;
  __shared__ float arow[NNODE];
  __shared__ float m1v[DD], m2v[DD];
  __shared__ float wv[4]; __shared__ int wi4[4];
  __shared__ float s_val[TOPK_]; __shared__ int s_idx[TOPK_];
  if (tid < DD) { m1v[tid] = m1[v * DD + tid]; m2v[tid] = m2[v * DD + tid]; }
  __syncthreads();
  for (int w = tid; w < NNODE; w += 256) {
    float d1 = 0.f, d2 = 0.f;
    #pragma unroll 8
    for (int k = 0; k < DD; k++) {
      d1 = fmaf(m1v[k], m2[w * DD + k], d1);
      d2 = fmaf(m2v[k], m1[w * DD + k], d2);
    }
    arow[w] = fmaxf(tanh_f(3.0f * (d1 - d2)), 0.0f);
  }
  __syncthreads();
  for (int sel = 0; sel < TOPK_; sel++) {
    float bv = -1.f; int bi = NNODE;
    for (int w = tid; w < NNODE; w += 256) {
      float xx = arow[w];
      if (xx > bv) { bv = xx; bi = w; }        // ascending scan => lowest idx on tie
    }
    for (int off = 32; off; off >>= 1) {
      float ov = __shfl_down(bv, off); int oi = __shfl_down(bi, off);
      if (ov > bv || (ov == bv && oi < bi)) { bv = ov; bi = oi; }
    }
    if (lane == 0) { wv[wave] = bv; wi4[wave] = bi; }
    __syncthreads();
    if (tid == 0) {
      float best = wv[0]; int besti = wi4[0];
      for (int t = 1; t < 4; t++)
        if (wv[t] > best || (wv[t] == best && wi4[t] < besti)) { best = wv[t]; besti = wi4[t]; }
      s_val[sel] = best; s_idx[sel] = besti;
      arow[besti] = -1.f;
    }
    __syncthreads();
  }
  if (tid == 0) {
    float rs = 1.0f;                       // diagonal contributes 1
    for (int e = 0; e < TOPK_; e++) rs += s_val[e];
    float inv = rcp_f(rs);
    pae[v * EPR] = make_int2(v, __float_as_int(inv));
    for (int e = 0; e < TOPK_; e++)
      pae[v * EPR + 1 + e] = make_int2(s_idx[e], __float_as_int(s_val[e] * inv));
  }
}

// ---------------- K3: LSTM over 12 steps, bf16 MFMA -------------------------
// Block = 256 thr = 4 waves; wave owns 16 sequences, computes all 256 gate cols.
// mfma_f32_16x16x32_bf16: A frag row=lane&15, k=(lane>>4)*8+e (consecutive 8);
// B frag col=lane&15 same k; D col=lane&15, row=(lane>>4)*4+reg  [m89/m92].
// Column remap: logical col L = nt*16 + c holds gate g=nt>>2, hidden
// j = c*4 + (nt&3).  => thread (c=arow) at acc[njt][i] owns (seq kg*4+i,
// j = arow*4+njt): i/f/g/o in SAME lane (tiles njt,njt+4,njt+8,njt+12) AND
// the thread's 4 j's are CONSECUTIVE -> h shuttle is one ds_write_b64, final
// h is a float4 store (fp32, closer to ref). h recirculates via LDS with
// __syncthreads() between write(t) and read(t+1). acc[] statically indexed
// (rule #20). Opaque-zero zo keeps whf loads loop-variant (no LICM spill).
__global__ __launch_bounds__(256, 2)
void k_lstm(const float* __restrict__ x, const float* __restrict__ Wih,
            const float* __restrict__ Whh, const float* __restrict__ bih,
            const float* __restrict__ bhh, float* __restrict__ hout) {
  __shared__ __align__(16) u16 whf[2 * 16 * 64 * 8];  // Whh frags [ks][nt][lane][8] (32 KB)
  __shared__ __align__(16) u16 hsh[4][16][64];        // per-wave h shuttle (8 KB)
  int tid = threadIdx.x, wave = tid >> 6, lane = tid & 63;
  int arow = lane & 15, kg = lane >> 4;

  // stage Whh frags: frag(ks,nt,l,e) = Whh[row=(nt>>2)*64+(l&15)*4+(nt&3)][ks*32+(l>>4)*8+e]
  for (int cc = tid; cc < 2 * 16 * 64; cc += 256) {
    int l = cc & 63, t16 = cc >> 6, ks = t16 >> 4, nt = t16 & 15;
    int row = (nt >> 2) * 64 + (l & 15) * 4 + (nt & 3);
    *(bf16x8*)&whf[cc * 8] = cvt8(Whh + row * 64 + ks * 32 + (l >> 4) * 8);
  }
  __syncthreads();

  bf16x8 wi[16];                                      // Wih fragments in registers
  float biasv[16];
  #pragma unroll
  for (int nt = 0; nt < 16; nt++) {
    int row = (nt >> 2) * 64 + arow * 4 + (nt & 3);
    wi[nt] = cvt8(Wih + row * 32 + kg * 8);
    biasv[nt] = bih[row] + bhh[row];
  }

  int seq_base = blockIdx.x * 64 + wave * 16;
  const float* xb = x + (size_t)(seq_base + arow) * (TT * FF) + kg * 8;
  float cst[16];
  #pragma unroll
  for (int q = 0; q < 16; q++) cst[q] = 0.f;
  fx4 acc[16];

  #pragma unroll 1
  for (int t = 0; t < TT; t++) {
    unsigned int zo = 0;                 // opaque zero, renewed each iteration:
    asm volatile("" : "+v"(zo));         // whf load addrs loop-variant => no LICM
    #pragma unroll
    for (int nt = 0; nt < 16; nt++)
      acc[nt] = (fx4){biasv[nt], biasv[nt], biasv[nt], biasv[nt]};
    bf16x8 xa = cvt8(xb + t * FF);
    #pragma unroll
    for (int nt = 0; nt < 16; nt++)
      acc[nt] = __builtin_amdgcn_mfma_f32_16x16x32_bf16(xa, wi[nt], acc[nt], 0, 0, 0);
    if (t > 0) {
      __syncthreads();                   // h shuttle: write(t-1) -> read(t)
      bf16x8 ha0 = *(const bf16x8*)&hsh[wave][arow][kg * 8];
      bf16x8 ha1 = *(const bf16x8*)&hsh[wave][arow][32 + kg * 8];
      #pragma unroll
      for (int nt = 0; nt < 16; nt++) {
        bf16x8 wb = *(const bf16x8*)&whf[(nt * 64 + lane) * 8 + zo];
        acc[nt] = __builtin_amdgcn_mfma_f32_16x16x32_bf16(ha0, wb, acc[nt], 0, 0, 0);
      }
      #pragma unroll
      for (int nt = 0; nt < 16; nt++) {
        bf16x8 wb = *(const bf16x8*)&whf[((16 + nt) * 64 + lane) * 8 + zo];
        acc[nt] = __builtin_amdgcn_mfma_f32_16x16x32_bf16(ha1, wb, acc[nt], 0, 0, 0);
      }
    }
    // gates: seq = kg*4+i, hidden j = arow*4+njt (consecutive in njt)
    #pragma unroll
    for (int i = 0; i < 4; i++) {
      float hq[4];
      #pragma unroll
      for (int njt = 0; njt < 4; njt++) {
        float iv = acc[njt][i], fv = acc[njt + 4][i];
        float gv = acc[njt + 8][i], ov = acc[njt + 12][i];
        float cpv = cst[i * 4 + njt];
        float c = sigm(fv) * cpv + sigm(iv) * tanh_f(gv);
        cst[i * 4 + njt] = c;
        hq[njt] = sigm(ov) * tanh_f(c);
      }
      if (t < TT - 1) {
        unsigned int p0 = cvt_pk(hq[0], hq[1]);
        unsigned int p1 = cvt_pk(hq[2], hq[3]);
        *(uint2*)&hsh[wave][kg * 4 + i][arow * 4] = make_uint2(p0, p1);
      } else {
        *(float4*)&hout[(size_t)(seq_base + kg * 4 + i) * HH + arow * 4] =
            (float4){hq[0], hq[1], hq[2], hq[3]};
      }
    }
  }
}

// ---------------- K_prep: layer-2 weights transposed into ws ----------------
// wt layout (all fp32): [0..767] lin_w^T [k][s]; [768..779] lin_b;
// [784..1935] mp1_w^T [c][o=32]; [1936..1967] mp1_b;
// [1968..5807] mp2_w^T [c][o=40]; [5808..5847] mp2_b.
__global__ void k_prep(const float* __restrict__ lw, const float* __restrict__ lb,
                       const float* __restrict__ w1, const float* __restrict__ b1,
                       const float* __restrict__ w2, const float* __restrict__ b2,
                       float* __restrict__ wt) {
  int tid = threadIdx.x;
  for (int i = tid; i < 768; i += 256) { int k = i / 12, s = i % 12; wt[i] = lw[s * 64 + k]; }
  if (tid < 12) wt[768 + tid] = lb[tid];
  for (int i = tid; i < 1152; i += 256) { int c = i / 32, o = i % 32; wt[784 + i] = w1[o * 36 + c]; }
  if (tid < 32) wt[1936 + tid] = b1[tid];
  for (int i = tid; i < 3840; i += 256) { int c = i / 40, o = i % 40; wt[1968 + i] = w2[o * 96 + c]; }
  if (tid < 40) wt[5808 + tid] = b2[tid];
}

// ---------------- K4: hj[b][s][n] = h[b*1000+n] . lin_w2[s] + lin_b2[s] -----
__global__ void k_hj(const float* __restrict__ h, const float* __restrict__ wt,
                     float* __restrict__ hj) {
  int id = blockIdx.x * 256 + threadIdx.x;     // (b,n), 64000 total
  int b = id / NNODE, n = id % NNODE;
  const float* hr = h + (size_t)id * HH;
  float hv[HH];
  #pragma unroll
  for (int k = 0; k < HH; k += 4) {
    float4 t4 = *(const float4*)(hr + k);
    hv[k] = t4.x; hv[k + 1] = t4.y; hv[k + 2] = t4.z; hv[k + 3] = t4.w;
  }
  float acc[12];
  #pragma unroll
  for (int s = 0; s < 12; s++) acc[s] = wt[768 + s];
  for (int k = 0; k < HH; k++) {
    float hvk = hv[k];
    #pragma unroll
    for (int s = 0; s < 12; s++) acc[s] = fmaf(hvk, wt[k * 12 + s], acc[s]);  // uniform -> SGPR
  }
  #pragma unroll
  for (int s = 0; s < 12; s++) hj[(size_t)(b * 12 + s) * NNODE + n] = acc[s];
}

// ---------------- K5/K7: mixprop propagation (gdep=2) -----------------------
// block = b*C + c. ho[b][d*C+c][:] for d=0,1,2 with h_{k+1}=0.05*x0+0.95*A h_k.
__global__ void k_prop(const float* __restrict__ hin, const int2* __restrict__ pae,
                       float* __restrict__ ho, int C) {
  int blk = blockIdx.x;
  int b = blk / C, c = blk % C;
  __shared__ float r0[NNODE], r1[NNODE];
  int tid = threadIdx.x;
  const float* src = hin + (size_t)(b * C + c) * NNODE;
  float* dst = ho + (size_t)(b * 3 * C) * NNODE;
  for (int n = tid; n < NNODE; n += 256) {
    float vv = src[n]; r0[n] = vv; dst[(size_t)c * NNODE + n] = vv;
  }
  __syncthreads();
  for (int n = tid; n < NNODE; n += 256) {
    const int2* pa = pae + n * EPR;
    float s = 0.f;
    #pragma unroll
    for (int e = 0; e < EPR; e++) { int2 p = pa[e]; s = fmaf(__int_as_float(p.y), r0[p.x], s); }
    float h1 = 0.05f * r0[n] + 0.95f * s;
    r1[n] = h1; dst[(size_t)(C + c) * NNODE + n] = h1;
  }
  __syncthreads();
  for (int n = tid; n < NNODE; n += 256) {
    const int2* pa = pae + n * EPR;
    float s = 0.f;
    #pragma unroll
    for (int e = 0; e < EPR; e++) { int2 p = pa[e]; s = fmaf(__int_as_float(p.y), r1[p.x], s); }
    dst[(size_t)(2 * C + c) * NNODE + n] = 0.05f * r0[n] + 0.95f * s;
  }
}

// ---------------- K6/K8: channel projection (uniform weights -> SGPR) -------
template <int CIN, int COUT>
__global__ void k_proj(const float* __restrict__ hin, const float* __restrict__ wt,
                       const float* __restrict__ bb, float* __restrict__ out, int relu) {
  int id = blockIdx.x * 256 + threadIdx.x;   // (b,n)
  int b = id / NNODE, n = id % NNODE;
  float acc[COUT];
  #pragma unroll
  for (int o = 0; o < COUT; o++) acc[o] = bb[o];
  for (int c = 0; c < CIN; c++) {
    float hv = hin[(size_t)(b * CIN + c) * NNODE + n];
    #pragma unroll
    for (int o = 0; o < COUT; o++) acc[o] = fmaf(hv, wt[c * COUT + o], acc[o]);
  }
  #pragma unroll
  for (int o = 0; o < COUT; o++) {
    float vv = acc[o];
    if (relu) vv = fmaxf(vv, 0.f);
    out[(size_t)(b * COUT + o) * NNODE + n] = vv;
  }
}

// ---------------- K9: layernorm stats over (40,1000) per batch --------------
__global__ void k_lnstat(const float* __restrict__ hj2, float* __restrict__ stat) {
  int b = blockIdx.x, tid = threadIdx.x, lane = tid & 63, wave = tid >> 6;
  const float* p = hj2 + (size_t)b * DD * NNODE;
  float s = 0.f, q = 0.f;
  for (int i = tid; i < DD * NNODE; i += 256) { float vv = p[i]; s += vv; q = fmaf(vv, vv, q); }
  for (int off = 32; off; off >>= 1) { s += __shfl_down(s, off); q += __shfl_down(q, off); }
  __shared__ float ss[4], sq[4];
  if (lane == 0) { ss[wave] = s; sq[wave] = q; }
  __syncthreads();
  if (tid == 0) {
    const float invN = 1.0f / (float)(DD * NNODE);
    float S = ss[0] + ss[1] + ss[2] + ss[3];
    float Q = sq[0] + sq[1] + sq[2] + sq[3];
    float mu = S * invN;
    float var = Q * invN - mu * mu;
    stat[2 * b] = mu; stat[2 * b + 1] = __builtin_amdgcn_rsqf(var + 1e-5f);
  }
}

// ---------------- K10: apply LN + transpose + fp32 out ----------------------
__global__ void k_lnapply(const float* __restrict__ hj2, const float* __restrict__ stat,
                          const float* __restrict__ gamma, const float* __restrict__ beta,
                          float* __restrict__ out) {
  int id = blockIdx.x * 256 + threadIdx.x;   // (b,n)
  int b = id / NNODE, n = id % NNODE;
  float mu = stat[2 * b], rstd = stat[2 * b + 1];
  size_t obase = (size_t)b * (NNODE * DD) + (size_t)n * DD;
  #pragma unroll
  for (int d0 = 0; d0 < DD / 4; d0++) {
    float tt[4];
    #pragma unroll
    for (int q = 0; q < 4; q++) {
      int d = d0 * 4 + q;
      float h0 = hj2[(size_t)(b * DD + d) * NNODE + n];
      tt[q] = (h0 - mu) * rstd * gamma[d * NNODE + n] + beta[d * NNODE + n];
    }
    *(float4*)(out + obase + d0 * 4) = (float4){tt[0], tt[1], tt[2], tt[3]};
  }
}

// ---------------- workspace layout (fp32 words) -----------------------------
// 0        m1(40000) | 40000 m2(40000) | 80000 pae(21000 int2 = 42000 words)
// 122000   h_lstm(4.096M)  [reused by ho2 after K4]
// 4218000  hj(768000) | 4986000 ho1(2.304M) | 7290000 o1(2.048M)
// 122000   ho2(6.144M)  [overlaps dead h_lstm/hj/ho1; ends 6266000 < 7290000]
// 9338000  hj2(2.56M) | 11898000 stat(128) | 11898128 wt(5848)   total ~47.6 MB
#define OFF_M1   0
#define OFF_M2   40000
#define OFF_PAE  80000
#define OFF_H    122000
#define OFF_HJ   4218000
#define OFF_HO1  4986000
#define OFF_O1   7290000
#define OFF_HO2  122000
#define OFF_HJ2  9338000
#define OFF_STAT 11898000
#define OFF_WT   11898128

extern "C" void kernel_launch(void* const* d_in, const int* in_sizes, int n_in,
                              void* d_out, int out_size, void* d_ws, size_t ws_size,
                              hipStream_t stream) {
  (void)in_sizes; (void)n_in; (void)out_size; (void)ws_size;
  const float* x     = (const float*)d_in[0];
  const float* emb1  = (const float*)d_in[1];
  const float* emb2  = (const float*)d_in[2];
  const float* l1w   = (const float*)d_in[3];
  const float* l1b   = (const float*)d_in[4];
  const float* l2w   = (const float*)d_in[5];
  const float* l2b   = (const float*)d_in[6];
  const float* Wih   = (const float*)d_in[7];
  const float* Whh   = (const float*)d_in[8];
  const float* bih   = (const float*)d_in[9];
  const float* bhh   = (const float*)d_in[10];
  const float* lin_w = (const float*)d_in[11];
  const float* lin_b = (const float*)d_in[12];
  const float* mp1w  = (const float*)d_in[13];
  const float* mp1b  = (const float*)d_in[14];
  const float* mp2w  = (const float*)d_in[15];
  const float* mp2b  = (const float*)d_in[16];
  const float* gamma = (const float*)d_in[17];
  const float* beta  = (const float*)d_in[18];

  float* ws   = (float*)d_ws;
  float* m1   = ws + OFF_M1;
  float* m2   = ws + OFF_M2;
  int2*  pae  = (int2*)(ws + OFF_PAE);
  float* hl   = ws + OFF_H;
  float* hj   = ws + OFF_HJ;
  float* ho1  = ws + OFF_HO1;
  float* o1   = ws + OFF_O1;
  float* ho2  = ws + OFF_HO2;
  float* hj2  = ws + OFF_HJ2;
  float* stat = ws + OFF_STAT;
  float* wt   = ws + OFF_WT;

  k_m1m2<<<dim3(313), dim3(256), 0, stream>>>(emb1, emb2, l1w, l1b, l2w, l2b, m1, m2);
  k_prep<<<dim3(1), dim3(256), 0, stream>>>(lin_w + 1536, lin_b + 24, mp1w + 2304, mp1b + 64,
                                            mp2w + 7680, mp2b + 80, wt);
  k_adj<<<dim3(NNODE), dim3(256), 0, stream>>>(m1, m2, pae);
  k_lstm<<<dim3(1000), dim3(256), 0, stream>>>(x, Wih, Whh, bih, bhh, hl);
  k_hj<<<dim3(250), dim3(256), 0, stream>>>(hl, wt, hj);
  k_prop<<<dim3(64 * 12), dim3(256), 0, stream>>>(hj, pae, ho1, 12);
  k_proj<36, 32><<<dim3(250), dim3(256), 0, stream>>>(ho1, wt + 784, wt + 1936, o1, 1);
  k_prop<<<dim3(64 * 32), dim3(256), 0, stream>>>(o1, pae, ho2, 32);
  k_proj<96, 40><<<dim3(250), dim3(256), 0, stream>>>(ho2, wt + 1968, wt + 5808, hj2, 0);
  k_lnstat<<<dim3(NB), dim3(256), 0, stream>>>(hj2, stat);
  k_lnapply<<<dim3(250), dim3(256), 0, stream>>>(hj2, stat, gamma + 80000, beta + 80000,
                                                 (float*)d_out);
}